// Round 15
// baseline (295.715 us; speedup 1.0000x reference)
//
#include <hip/hip_runtime.h>

#define D 64
#define KC 512
#define EMA_A 0.01f
#define SROWS 1024     // rows per segsum block
#define NCHUNK 256     // N / SROWS (gpart + gcount partials)
#define BAND 0.015625f // recheck band; 3-term split err ~7e-4 -> ~20x margin

typedef float f32x4 __attribute__((ext_vector_type(4)));
typedef float v4f __attribute__((ext_vector_type(4)));
typedef short s8v __attribute__((ext_vector_type(8)));   // 8 bf16 as shorts
typedef short s4v __attribute__((ext_vector_type(4)));

__device__ inline unsigned short bf16_rne(float f) {
    unsigned u = __float_as_uint(f);
    return (unsigned short)((u + 0x7fffu + ((u >> 16) & 1u)) >> 16);
}
__device__ inline float bf16_f(unsigned short h) {
    return __uint_as_float(((unsigned)h) << 16);
}
__device__ inline float med3f(float a, float b, float c) {
#if __has_builtin(__builtin_amdgcn_fmed3f)
    return __builtin_amdgcn_fmed3f(a, b, c);
#else
    return fmaxf(fminf(a, fmaxf(b, c)), fminf(b, c));
#endif
}

// ---- K0: he[k] = 0.5*||emb_k||^2 ; pre-SWIZZLED bf16 hi/lo B images
//          (XOR swizzle: B consumed via ds_read_b128) ; zero worklist ----
__global__ __launch_bounds__(256) void k_prep(const float* __restrict__ emb,
                                              float* __restrict__ he,
                                              short* __restrict__ gB,
                                              int* __restrict__ wcount) {
    if (blockIdx.x == 0 && threadIdx.x == 0) wcount[0] = 0;
    int k = blockIdx.x * 256 + threadIdx.x;
    if (k >= KC) return;
    int c8 = k >> 6, c = k & 63;
    short* dst = gB + (size_t)c8 * 8192;
    float s = 0.f;
#pragma unroll
    for (int kq = 0; kq < 16; ++kq) {
        float4 v = ((const float4*)(emb + (size_t)k * D))[kq];
        s = fmaf(v.x, v.x, s); s = fmaf(v.y, v.y, s);
        s = fmaf(v.z, v.z, s); s = fmaf(v.w, v.w, s);
        unsigned short h0 = bf16_rne(v.x), h1 = bf16_rne(v.y);
        unsigned short h2 = bf16_rne(v.z), h3 = bf16_rne(v.w);
        s4v hv = {(short)h0, (short)h1, (short)h2, (short)h3};
        s4v lv = {(short)bf16_rne(v.x - bf16_f(h0)),
                  (short)bf16_rne(v.y - bf16_f(h1)),
                  (short)bf16_rne(v.z - bf16_f(h2)),
                  (short)bf16_rne(v.w - bf16_f(h3))};
        int si = c * 64 + (((kq >> 1) ^ (c & 7)) * 8) + (kq & 1) * 4;
        *(s4v*)(&dst[si]) = hv;
        *(s4v*)(&dst[4096 + si]) = lv;
    }
    he[k] = 0.5f * s;
}

// ---- K1: MFMA 3-term split-bf16 argmin — half-B-in-LDS, TRUE 2 blocks/CU.
// Occupancy-arc resolution (r10-r14): per-SIMD VGPR pool = 2048 (m69), so
// 2 blocks/CU (16 waves) needs VGPR <= ~120. r12's (512,2) bound pinned
// exactly 128 -> 16x128 = 2048 + granularity -> 2nd block NEVER resident
// (Occupancy stayed at r9's 1-block 20%) while paying a 12.7MB spill.
// r14 proved this exact body allocates 88 VGPR under plain
// __launch_bounds__(512) with zero spill. 88*16 = 1408 << 2048. So:
// r14 body + 64KiB half-B restage + plain bounds = the one untested
// combination where 2 blocks/CU actually materializes. Restage barrier
// hides under the co-resident block's compute (m114 overlap).
// Tripwires: VGPR > 120 or WRITE >> 1MB -> theory failed.
__global__ __launch_bounds__(512) void k_assign(
    const float* __restrict__ x, const short* __restrict__ gB,
    const float* __restrict__ he, int* __restrict__ idx,
    int* __restrict__ wlist, int* __restrict__ wcount) {
    __shared__ __align__(16) short LB[32768];  // 64 KiB: half B image
    int tid = threadIdx.x;
    int lane = tid & 63, w = tid >> 6, q = lane >> 4, c16 = lane & 15;
    size_t R0 = (size_t)blockIdx.x * 256;   // 256 rows per block

    // stage half 0 (clusters 0-255): 4096 int4 over 512 threads
    {
        const int4* gsrc = (const int4*)gB;
        int4* ldst = (int4*)LB;
#pragma unroll
        for (int p = 0; p < 8; ++p) ldst[p * 512 + tid] = gsrc[p * 512 + tid];
    }

    // A fragments for 2 M-tiles: lane (c16,q) of wave w owns rows
    // w*32 + mt*16 + c16, k-group g = ks*4+q. Convert to bf16 hi/lo.
    s8v ah[2][2], al[2][2];
#pragma unroll
    for (int mt = 0; mt < 2; ++mt) {
        const float* xr = x + (R0 + (size_t)(w * 32 + mt * 16 + c16)) * D;
#pragma unroll
        for (int ks = 0; ks < 2; ++ks) {
            int g = ks * 4 + q;
            f32x4 v0 = *(const f32x4*)(xr + g * 8);
            f32x4 v1 = *(const f32x4*)(xr + g * 8 + 4);
#pragma unroll
            for (int j = 0; j < 4; ++j) {
                unsigned short h0 = bf16_rne(v0[j]);
                ah[mt][ks][j] = (short)h0;
                al[mt][ks][j] = (short)bf16_rne(v0[j] - bf16_f(h0));
                unsigned short h1 = bf16_rne(v1[j]);
                ah[mt][ks][4 + j] = (short)h1;
                al[mt][ks][4 + j] = (short)bf16_rne(v1[j] - bf16_f(h1));
            }
        }
    }
    __syncthreads();   // half 0 staged

    // max-form tracking: s = dot - he = -d; argmin d == argmax s
    float m1[2][4], m2[2][4]; int i1[2][4];
#pragma unroll
    for (int mt = 0; mt < 2; ++mt)
#pragma unroll
        for (int e = 0; e < 4; ++e) {
            m1[mt][e] = -3.4e38f; m2[mt][e] = -3.4e38f; i1[mt][e] = 0;
        }

    for (int half = 0; half < 2; ++half) {
        if (half == 1) {
            __syncthreads();   // all waves done reading half 0
            const int4* gsrc = ((const int4*)gB) + 4096;
            int4* ldst = (int4*)LB;
#pragma unroll
            for (int p = 0; p < 8; ++p)
                ldst[p * 512 + tid] = gsrc[p * 512 + tid];
            __syncthreads();   // half 1 staged
        }
#pragma unroll
        for (int cc = 0; cc < 4; ++cc) {
            const short* B = LB + cc * 8192;
            int c8 = half * 4 + cc;
#pragma unroll
            for (int ct = 0; ct < 4; ++ct) {
                int c = ct * 16 + c16;
                s8v bh[2], bl[2];
#pragma unroll
                for (int ks = 0; ks < 2; ++ks) {
                    int kb = (ks * 4 + q) ^ (c & 7);
                    bh[ks] = *(const s8v*)(&B[c * 64 + kb * 8]);
                    bl[ks] = *(const s8v*)(&B[4096 + c * 64 + kb * 8]);
                }
                int cbase = c8 * 64 + ct * 16;
                float hn = -he[cbase + c16];
                int ci = cbase + c16;
#pragma unroll
                for (int mt = 0; mt < 2; ++mt) {
                    f32x4 a0 = {hn, hn, hn, hn};   // C-init = -he
                    f32x4 a1 = {0.f, 0.f, 0.f, 0.f};
                    a0 = __builtin_amdgcn_mfma_f32_16x16x32_bf16(ah[mt][0], bh[0], a0, 0, 0, 0);
                    a0 = __builtin_amdgcn_mfma_f32_16x16x32_bf16(ah[mt][1], bh[1], a0, 0, 0, 0);
                    a0 = __builtin_amdgcn_mfma_f32_16x16x32_bf16(ah[mt][0], bl[0], a0, 0, 0, 0);
                    a0 = __builtin_amdgcn_mfma_f32_16x16x32_bf16(ah[mt][1], bl[1], a0, 0, 0, 0);
                    a1 = __builtin_amdgcn_mfma_f32_16x16x32_bf16(al[mt][0], bh[0], a1, 0, 0, 0);
                    a1 = __builtin_amdgcn_mfma_f32_16x16x32_bf16(al[mt][1], bh[1], a1, 0, 0, 0);
#pragma unroll
                    for (int r = 0; r < 4; ++r) {
                        float s = a0[r] + a1[r];
                        m2[mt][r] = med3f(s, m2[mt][r], m1[mt][r]);  // 2nd-max
                        bool gt = s > m1[mt][r];           // strict: first-max
                        i1[mt][r] = gt ? ci : i1[mt][r];
                        m1[mt][r] = fmaxf(m1[mt][r], s);
                    }
                }
            }
        }
    }
    // reduce (m1,i1,m2) across the 16 lanes of each quad group (max-form)
#pragma unroll
    for (int m = 1; m < 16; m <<= 1) {
#pragma unroll
        for (int mt = 0; mt < 2; ++mt)
#pragma unroll
            for (int e = 0; e < 4; ++e) {
                float om1 = __shfl_xor(m1[mt][e], m);
                float om2 = __shfl_xor(m2[mt][e], m);
                int oi = __shfl_xor(i1[mt][e], m);
                float nm2 = fmaxf(fmaxf(m2[mt][e], om2), fminf(m1[mt][e], om1));
                bool take = (om1 > m1[mt][e]) || (om1 == m1[mt][e] && oi < i1[mt][e]);
                i1[mt][e] = take ? oi : i1[mt][e];
                m1[mt][e] = fmaxf(m1[mt][e], om1);
                m2[mt][e] = nm2;
            }
    }
    // ---- epilogue: worklist aliases into LB (B image is dead now) ----
    __syncthreads();                    // all waves done reading LB
    int* wl = (int*)LB;                 // wl[0]=cnt, wl[1]=base, wl[2..]=rows
    if (tid == 0) wl[0] = 0;
    __syncthreads();
    if (c16 == 0) {
#pragma unroll
        for (int mt = 0; mt < 2; ++mt)
#pragma unroll
            for (int e = 0; e < 4; ++e) {
                int row = (int)R0 + w * 32 + mt * 16 + q * 4 + e;
                idx[row] = i1[mt][e];
                if (m1[mt][e] - m2[mt][e] < BAND) {   // margin band (max-form)
                    int p = atomicAdd(&wl[0], 1);     // LDS atomic; max 256
                    wl[2 + p] = row;
                }
            }
    }
    __syncthreads();
    if (tid == 0 && wl[0] > 0) wl[1] = atomicAdd(wcount, wl[0]);
    __syncthreads();
    int wcnt = wl[0];
    for (int i = tid; i < wcnt; i += 512) wlist[wl[1] + i] = wl[2 + i];
}

// ---- K1b: exact fp32 rescan, one WAVE per worklist row ----
// hardened: clamp cnt and row so poisoned workspace can never go OOB
__global__ __launch_bounds__(256) void k_recheck(
    const float* __restrict__ x, const float* __restrict__ emb,
    const float* __restrict__ he, const int* __restrict__ wlist,
    const int* __restrict__ wcount, int* __restrict__ idx, int nrows) {
    int lane = threadIdx.x & 63;
    int wave = (blockIdx.x * 256 + threadIdx.x) >> 6;
    int nwaves = (gridDim.x * 256) >> 6;
    int cnt = wcount[0];
    if (cnt < 0) cnt = 0;
    if (cnt > nrows) cnt = nrows;
    for (int i = wave; i < cnt; i += nwaves) {
        int row = wlist[i];
        if ((unsigned)row >= (unsigned)nrows) continue;  // defensive
        const v4f* xr = (const v4f*)(x + (size_t)row * D);
        v4f X[16];
#pragma unroll
        for (int t = 0; t < 16; ++t) X[t] = xr[t];
        float bd = 3.4e38f; int bi = 0x7fffffff;
#pragma unroll
        for (int j = 0; j < 8; ++j) {
            int c = j * 64 + lane;
            const v4f* er = (const v4f*)(emb + (size_t)c * D);
            v4f s = X[0] * er[0];
#pragma unroll
            for (int t = 1; t < 16; ++t) s += X[t] * er[t];
            float dot = (s.x + s.y) + (s.z + s.w);
            float d = he[c] - dot;
            if (d < bd) { bd = d; bi = c; }
        }
#pragma unroll
        for (int m = 1; m < 64; m <<= 1) {
            float od = __shfl_xor(bd, m);
            int oi = __shfl_xor(bi, m);
            if (od < bd || (od == bd && oi < bi)) { bd = od; bi = oi; }
        }
        if (lane == 0) idx[row] = bi;
    }
}

// ---- K2: MFMA one-hot segment sums + FUSED count histogram ----
// 64-row x staging (barriers 64 -> 34); hist over LDS while sidx is hot.
// gpart partials stored as fp16 (range OK; rel err 2^-11 -> <~1e-3 on
// embnew after 256-partial sum + 0.01 EMA).
__global__ __launch_bounds__(512, 1) void k_segsum(
    const float* __restrict__ x, const int* __restrict__ idx,
    _Float16* __restrict__ gpart, float* __restrict__ gcount) {
    __shared__ int sidx[SROWS];          // 4 KB
    __shared__ unsigned xpk[64 * 64];    // 16 KB
    __shared__ int hist[KC];             // 2 KB
    int tid = threadIdx.x;
    int lane = tid & 63, w = tid >> 6, q = lane >> 4, c16 = lane & 15;
    int nb0 = blockIdx.x * SROWS;
    for (int i = tid; i < SROWS; i += 512) sidx[i] = idx[nb0 + i];
    hist[tid] = 0;   // blockDim == KC == 512
    __syncthreads();
    for (int i = tid; i < SROWS; i += 512) atomicAdd(&hist[sidx[i] & (KC - 1)], 1);

    f32x4 acc[4][4];
#pragma unroll
    for (int a = 0; a < 4; ++a)
#pragma unroll
        for (int b = 0; b < 4; ++b) acc[a][b] = (f32x4){0.f, 0.f, 0.f, 0.f};

    for (int ch = 0; ch < SROWS / 64; ++ch) {
        __syncthreads();  // xpk reuse (and hist atomics done by first iter)
#pragma unroll
        for (int pp = 0; pp < 2; ++pp) {
            int flat = pp * 512 + tid;
            int r64 = flat >> 4, d4 = flat & 15;
            float4 v = ((const float4*)(x + (size_t)(nb0 + ch * 64 + r64) * D))[d4];
            float vals[4] = {v.x, v.y, v.z, v.w};
#pragma unroll
            for (int i = 0; i < 4; ++i) {
                unsigned short h = bf16_rne(vals[i]);
                unsigned short l = bf16_rne(vals[i] - bf16_f(h));
                int d = d4 * 4 + i;
                xpk[r64 * 64 + ((d + 2 * r64) & 63)] =
                    (unsigned)h | ((unsigned)l << 16);
            }
        }
        __syncthreads();
#pragma unroll
        for (int s = 0; s < 2; ++s) {
            int iv[8];
#pragma unroll
            for (int j = 0; j < 8; ++j)
                iv[j] = sidx[ch * 64 + s * 32 + q * 8 + j];
            s8v af[4];
#pragma unroll
            for (int kt = 0; kt < 4; ++kt) {
                int tgt = w * 64 + kt * 16 + c16;
#pragma unroll
                for (int j = 0; j < 8; ++j)
                    af[kt][j] = (iv[j] == tgt) ? (short)0x3F80 : (short)0;
            }
#pragma unroll
            for (int dt = 0; dt < 4; ++dt) {
                s8v bh, bl;
#pragma unroll
                for (int j = 0; j < 8; ++j) {
                    int n = s * 32 + q * 8 + j;
                    unsigned pv = xpk[n * 64 + ((dt * 16 + c16 + 2 * n) & 63)];
                    bh[j] = (short)(pv & 0xffff);
                    bl[j] = (short)(pv >> 16);
                }
#pragma unroll
                for (int kt = 0; kt < 4; ++kt) {
                    acc[kt][dt] = __builtin_amdgcn_mfma_f32_16x16x32_bf16(af[kt], bh, acc[kt][dt], 0, 0, 0);
                    acc[kt][dt] = __builtin_amdgcn_mfma_f32_16x16x32_bf16(af[kt], bl, acc[kt][dt], 0, 0, 0);
                }
            }
        }
    }
    _Float16* gp = gpart + (size_t)blockIdx.x * (KC * D);
#pragma unroll
    for (int kt = 0; kt < 4; ++kt)
#pragma unroll
        for (int dt = 0; dt < 4; ++dt)
#pragma unroll
            for (int r = 0; r < 4; ++r) {
                int k = w * 64 + kt * 16 + q * 4 + r;
                gp[k * D + dt * 16 + c16] = (_Float16)acc[kt][dt][r];
            }
    __syncthreads();
    gcount[(size_t)blockIdx.x * KC + tid] = (float)hist[tid];
}

// ---- K3: one block per cluster: reduce gpart+gcount + EMA -> embedding_new --
// usage==0 clusters never appear in encoding_index -> flat[r] path is dead.
__global__ __launch_bounds__(256) void k_final(
    const _Float16* __restrict__ gpart, const float* __restrict__ gcount,
    const float* __restrict__ cnt_in, const float* __restrict__ sum_embed,
    float* __restrict__ embnew) {
    __shared__ float sp[4][64];
    __shared__ float cp[256];
    int k = blockIdx.x;               // 512 blocks = KC
    int tid = threadIdx.x;
    int d = tid & 63, g = tid >> 6;
    float s = 0.f;
    for (int c = g * 64; c < g * 64 + 64; ++c)
        s += (float)gpart[(size_t)c * (KC * D) + k * D + d];
    sp[g][d] = s;
    cp[tid] = gcount[(size_t)tid * KC + k];
    __syncthreads();
    if (g == 0) {
        float st = sp[0][d] + sp[1][d] + sp[2][d] + sp[3][d];
        float cv = cp[4 * d] + cp[4 * d + 1] + cp[4 * d + 2] + cp[4 * d + 3];
#pragma unroll
        for (int m = 1; m < 64; m <<= 1) cv += __shfl_xor(cv, m);
        float c0 = cnt_in[k];
        float cn = c0 + EMA_A * (cv - c0);
        float se0 = sum_embed[k * D + d];
        float se = se0 + EMA_A * (st - se0);
        embnew[k * D + d] = (cn >= 1.0f) ? (se / cn) : 0.0f;
    }
}

// ---- K4: gather out[n][:] = embnew[idx[n]][:] ----
// idx masked to [0,KC) so a poisoned idx can never read OOB (no-op when valid)
__global__ __launch_bounds__(256) void k_gather(const int* __restrict__ idx,
                                                const float* __restrict__ embnew,
                                                float* __restrict__ out, int N) {
    int g = blockIdx.x * 256 + threadIdx.x;
    int row = g >> 4, q = g & 15;
    if (row >= N) return;
    int k = idx[row] & (KC - 1);
    const float4* e4 = (const float4*)embnew;
    ((float4*)out)[(size_t)row * (D / 4) + q] = e4[k * (D / 4) + q];
}

extern "C" void kernel_launch(void* const* d_in, const int* in_sizes, int n_in,
                              void* d_out, int out_size, void* d_ws, size_t ws_size,
                              hipStream_t stream) {
    const float* x = (const float*)d_in[0];
    const float* emb = (const float*)d_in[1];
    const float* cnt = (const float*)d_in[2];
    const float* sum_embed = (const float*)d_in[3];
    float* out = (float*)d_out;
    int N = in_sizes[0] / D;  // 262144

    char* w = (char*)d_ws;
    size_t off = 0;
    int* idx = (int*)(w + off);        off += (size_t)N * 4;                 // 1 MB
    int* wlist = (int*)(w + off);      off += (size_t)N * 4;                 // 1 MB
    int* wcount = (int*)(w + off);     off += 16;
    float* he = (float*)(w + off);     off += (size_t)KC * 4;                // 2 KB
    short* gB = (short*)(w + off);     off += (size_t)8 * 8192 * 2;          // 128 KB
    float* embnew = (float*)(w + off); off += (size_t)KC * D * 4;            // 128 KB
    float* gcount = (float*)(w + off); off += (size_t)NCHUNK * KC * 4;       // 512 KB
    _Float16* gpart = (_Float16*)(w + off);
    off += (size_t)NCHUNK * KC * D * 2;                                      // 16 MB
    // total ~19.7 MB

    k_prep<<<(KC + 255) / 256, 256, 0, stream>>>(emb, he, gB, wcount);
    k_assign<<<N / 256, 512, 0, stream>>>(x, gB, he, idx, wlist, wcount);
    k_recheck<<<512, 256, 0, stream>>>(x, emb, he, wlist, wcount, idx, N);
    k_segsum<<<NCHUNK, 512, 0, stream>>>(x, idx, gpart, gcount);
    k_final<<<KC, 256, 0, stream>>>(gpart, gcount, cnt, sum_embed, embnew);
    k_gather<<<((size_t)N * (D / 4)) / 256, 256, 0, stream>>>(idx, embnew, out, N);
}

// Round 16
// 275.358 us; speedup vs baseline: 1.0739x; 1.0739x over previous
//
#include <hip/hip_runtime.h>

#define D 64
#define KC 512
#define EMA_A 0.01f
#define SROWS 1024     // rows per segsum block
#define NCHUNK 256     // N / SROWS (gpart + gcount partials)
#define BAND 0.015625f // recheck band; 3-term split err ~7e-4 -> ~20x margin

typedef float f32x4 __attribute__((ext_vector_type(4)));
typedef float v4f __attribute__((ext_vector_type(4)));
typedef short s8v __attribute__((ext_vector_type(8)));   // 8 bf16 as shorts
typedef short s4v __attribute__((ext_vector_type(4)));

__device__ inline unsigned short bf16_rne(float f) {
    unsigned u = __float_as_uint(f);
    return (unsigned short)((u + 0x7fffu + ((u >> 16) & 1u)) >> 16);
}
__device__ inline float bf16_f(unsigned short h) {
    return __uint_as_float(((unsigned)h) << 16);
}
__device__ inline float med3f(float a, float b, float c) {
#if __has_builtin(__builtin_amdgcn_fmed3f)
    return __builtin_amdgcn_fmed3f(a, b, c);
#else
    return fmaxf(fminf(a, fmaxf(b, c)), fminf(b, c));
#endif
}

// ---- K0: he[k] = 0.5*||emb_k||^2 ; pre-SWIZZLED bf16 hi/lo B images
//          (XOR swizzle: B consumed via ds_read_b128) ; zero worklist ----
__global__ __launch_bounds__(256) void k_prep(const float* __restrict__ emb,
                                              float* __restrict__ he,
                                              short* __restrict__ gB,
                                              int* __restrict__ wcount) {
    if (blockIdx.x == 0 && threadIdx.x == 0) wcount[0] = 0;
    int k = blockIdx.x * 256 + threadIdx.x;
    if (k >= KC) return;
    int c8 = k >> 6, c = k & 63;
    short* dst = gB + (size_t)c8 * 8192;
    float s = 0.f;
#pragma unroll
    for (int kq = 0; kq < 16; ++kq) {
        float4 v = ((const float4*)(emb + (size_t)k * D))[kq];
        s = fmaf(v.x, v.x, s); s = fmaf(v.y, v.y, s);
        s = fmaf(v.z, v.z, s); s = fmaf(v.w, v.w, s);
        unsigned short h0 = bf16_rne(v.x), h1 = bf16_rne(v.y);
        unsigned short h2 = bf16_rne(v.z), h3 = bf16_rne(v.w);
        s4v hv = {(short)h0, (short)h1, (short)h2, (short)h3};
        s4v lv = {(short)bf16_rne(v.x - bf16_f(h0)),
                  (short)bf16_rne(v.y - bf16_f(h1)),
                  (short)bf16_rne(v.z - bf16_f(h2)),
                  (short)bf16_rne(v.w - bf16_f(h3))};
        int si = c * 64 + (((kq >> 1) ^ (c & 7)) * 8) + (kq & 1) * 4;
        *(s4v*)(&dst[si]) = hv;
        *(s4v*)(&dst[4096 + si]) = lv;
    }
    he[k] = 0.5f * s;
}

// ---- K1: MFMA 3-term split-bf16 argmin — whole-B-in-LDS, zero-barrier loop.
// = r14 champion EXACTLY (84us, 88 VGPR, no spill). Occupancy arc closed:
// r10/r11/r12/r13/r15 all failed (spill or phantom occupancy) — with 64KiB
// LDS the compiler targets 2 blocks/CU, caps at 128 regs, hoists restage
// loads across compute (cross-phase hold) and spills; Occupancy never rose.
// 128KiB whole-B + plain bounds lets the allocator pick 88 regs, no spill.
// he-fold + max-form med3 tracking grafted (validated r10-r14).
__global__ __launch_bounds__(512) void k_assign(
    const float* __restrict__ x, const short* __restrict__ gB,
    const float* __restrict__ he, int* __restrict__ idx,
    int* __restrict__ wlist, int* __restrict__ wcount) {
    __shared__ __align__(16) short LB[65536];  // 128 KiB exactly
    int tid = threadIdx.x;
    int lane = tid & 63, w = tid >> 6, q = lane >> 4, c16 = lane & 15;
    size_t R0 = (size_t)blockIdx.x * 256;   // 256 rows per block

    // stage full pre-swizzled B image: 8192 int4 over 512 threads
    {
        const int4* gsrc = (const int4*)gB;
        int4* ldst = (int4*)LB;
#pragma unroll
        for (int p = 0; p < 16; ++p) ldst[p * 512 + tid] = gsrc[p * 512 + tid];
    }

    // A fragments for 2 M-tiles: lane (c16,q) of wave w owns rows
    // w*32 + mt*16 + c16, k-group g = ks*4+q. Convert to bf16 hi/lo.
    s8v ah[2][2], al[2][2];
#pragma unroll
    for (int mt = 0; mt < 2; ++mt) {
        const float* xr = x + (R0 + (size_t)(w * 32 + mt * 16 + c16)) * D;
#pragma unroll
        for (int ks = 0; ks < 2; ++ks) {
            int g = ks * 4 + q;
            f32x4 v0 = *(const f32x4*)(xr + g * 8);
            f32x4 v1 = *(const f32x4*)(xr + g * 8 + 4);
#pragma unroll
            for (int j = 0; j < 4; ++j) {
                unsigned short h0 = bf16_rne(v0[j]);
                ah[mt][ks][j] = (short)h0;
                al[mt][ks][j] = (short)bf16_rne(v0[j] - bf16_f(h0));
                unsigned short h1 = bf16_rne(v1[j]);
                ah[mt][ks][4 + j] = (short)h1;
                al[mt][ks][4 + j] = (short)bf16_rne(v1[j] - bf16_f(h1));
            }
        }
    }
    __syncthreads();   // B image staged (the only barrier before epilogue)

    // max-form tracking: s = dot - he = -d; argmin d == argmax s
    float m1[2][4], m2[2][4]; int i1[2][4];
#pragma unroll
    for (int mt = 0; mt < 2; ++mt)
#pragma unroll
        for (int e = 0; e < 4; ++e) {
            m1[mt][e] = -3.4e38f; m2[mt][e] = -3.4e38f; i1[mt][e] = 0;
        }

#pragma unroll
    for (int c8 = 0; c8 < 8; ++c8) {
        const short* B = LB + c8 * 8192;
#pragma unroll
        for (int ct = 0; ct < 4; ++ct) {
            int c = ct * 16 + c16;
            s8v bh[2], bl[2];
#pragma unroll
            for (int ks = 0; ks < 2; ++ks) {
                int kb = (ks * 4 + q) ^ (c & 7);
                bh[ks] = *(const s8v*)(&B[c * 64 + kb * 8]);
                bl[ks] = *(const s8v*)(&B[4096 + c * 64 + kb * 8]);
            }
            int cbase = c8 * 64 + ct * 16;
            float hn = -he[cbase + c16];
            int ci = cbase + c16;
#pragma unroll
            for (int mt = 0; mt < 2; ++mt) {
                f32x4 a0 = {hn, hn, hn, hn};   // C-init = -he
                f32x4 a1 = {0.f, 0.f, 0.f, 0.f};
                a0 = __builtin_amdgcn_mfma_f32_16x16x32_bf16(ah[mt][0], bh[0], a0, 0, 0, 0);
                a0 = __builtin_amdgcn_mfma_f32_16x16x32_bf16(ah[mt][1], bh[1], a0, 0, 0, 0);
                a0 = __builtin_amdgcn_mfma_f32_16x16x32_bf16(ah[mt][0], bl[0], a0, 0, 0, 0);
                a0 = __builtin_amdgcn_mfma_f32_16x16x32_bf16(ah[mt][1], bl[1], a0, 0, 0, 0);
                a1 = __builtin_amdgcn_mfma_f32_16x16x32_bf16(al[mt][0], bh[0], a1, 0, 0, 0);
                a1 = __builtin_amdgcn_mfma_f32_16x16x32_bf16(al[mt][1], bh[1], a1, 0, 0, 0);
#pragma unroll
                for (int r = 0; r < 4; ++r) {
                    float s = a0[r] + a1[r];
                    m2[mt][r] = med3f(s, m2[mt][r], m1[mt][r]);  // 2nd-max
                    bool gt = s > m1[mt][r];            // strict: first-max
                    i1[mt][r] = gt ? ci : i1[mt][r];
                    m1[mt][r] = fmaxf(m1[mt][r], s);
                }
            }
        }
    }
    // reduce (m1,i1,m2) across the 16 lanes of each quad group (max-form)
#pragma unroll
    for (int m = 1; m < 16; m <<= 1) {
#pragma unroll
        for (int mt = 0; mt < 2; ++mt)
#pragma unroll
            for (int e = 0; e < 4; ++e) {
                float om1 = __shfl_xor(m1[mt][e], m);
                float om2 = __shfl_xor(m2[mt][e], m);
                int oi = __shfl_xor(i1[mt][e], m);
                float nm2 = fmaxf(fmaxf(m2[mt][e], om2), fminf(m1[mt][e], om1));
                bool take = (om1 > m1[mt][e]) || (om1 == m1[mt][e] && oi < i1[mt][e]);
                i1[mt][e] = take ? oi : i1[mt][e];
                m1[mt][e] = fmaxf(m1[mt][e], om1);
                m2[mt][e] = nm2;
            }
    }
    // ---- epilogue: worklist aliases into LB (B image is dead now) ----
    __syncthreads();                    // all waves done reading LB
    int* wl = (int*)LB;                 // wl[0]=cnt, wl[1]=base, wl[2..]=rows
    if (tid == 0) wl[0] = 0;
    __syncthreads();
    if (c16 == 0) {
#pragma unroll
        for (int mt = 0; mt < 2; ++mt)
#pragma unroll
            for (int e = 0; e < 4; ++e) {
                int row = (int)R0 + w * 32 + mt * 16 + q * 4 + e;
                idx[row] = i1[mt][e];
                if (m1[mt][e] - m2[mt][e] < BAND) {   // margin band (max-form)
                    int p = atomicAdd(&wl[0], 1);     // LDS atomic; max 256
                    wl[2 + p] = row;
                }
            }
    }
    __syncthreads();
    if (tid == 0 && wl[0] > 0) wl[1] = atomicAdd(wcount, wl[0]);
    __syncthreads();
    int wcnt = wl[0];
    for (int i = tid; i < wcnt; i += 512) wlist[wl[1] + i] = wl[2 + i];
}

// ---- K1b: exact fp32 rescan, one WAVE per worklist row ----
// hardened: clamp cnt and row so poisoned workspace can never go OOB
__global__ __launch_bounds__(256) void k_recheck(
    const float* __restrict__ x, const float* __restrict__ emb,
    const float* __restrict__ he, const int* __restrict__ wlist,
    const int* __restrict__ wcount, int* __restrict__ idx, int nrows) {
    int lane = threadIdx.x & 63;
    int wave = (blockIdx.x * 256 + threadIdx.x) >> 6;
    int nwaves = (gridDim.x * 256) >> 6;
    int cnt = wcount[0];
    if (cnt < 0) cnt = 0;
    if (cnt > nrows) cnt = nrows;
    for (int i = wave; i < cnt; i += nwaves) {
        int row = wlist[i];
        if ((unsigned)row >= (unsigned)nrows) continue;  // defensive
        const v4f* xr = (const v4f*)(x + (size_t)row * D);
        v4f X[16];
#pragma unroll
        for (int t = 0; t < 16; ++t) X[t] = xr[t];
        float bd = 3.4e38f; int bi = 0x7fffffff;
#pragma unroll
        for (int j = 0; j < 8; ++j) {
            int c = j * 64 + lane;
            const v4f* er = (const v4f*)(emb + (size_t)c * D);
            v4f s = X[0] * er[0];
#pragma unroll
            for (int t = 1; t < 16; ++t) s += X[t] * er[t];
            float dot = (s.x + s.y) + (s.z + s.w);
            float d = he[c] - dot;
            if (d < bd) { bd = d; bi = c; }
        }
#pragma unroll
        for (int m = 1; m < 64; m <<= 1) {
            float od = __shfl_xor(bd, m);
            int oi = __shfl_xor(bi, m);
            if (od < bd || (od == bd && oi < bi)) { bd = od; bi = oi; }
        }
        if (lane == 0) idx[row] = bi;
    }
}

// ---- K2: MFMA one-hot segment sums + FUSED count histogram ----
// HI-ONLY bf16 x image (lo image dropped): segment sums feed a 0.01-weight
// EMA, so bf16 per-element rounding (2^-8 rel) contributes ~1e-4 on embnew
// — two orders under the 0.0078 current absmax, threshold 0.063. Halves
// the MFMA stream (1024 -> 512 per wave) and cuts ~40% of the staging
// conversion VALU. Layout/swizzle/hist byte-identical otherwise.
// gpart partials stored as fp16 (validated r1+).
__global__ __launch_bounds__(512, 1) void k_segsum(
    const float* __restrict__ x, const int* __restrict__ idx,
    _Float16* __restrict__ gpart, float* __restrict__ gcount) {
    __shared__ int sidx[SROWS];          // 4 KB
    __shared__ unsigned xpk[64 * 64];    // 16 KB (hi in low 16 bits)
    __shared__ int hist[KC];             // 2 KB
    int tid = threadIdx.x;
    int lane = tid & 63, w = tid >> 6, q = lane >> 4, c16 = lane & 15;
    int nb0 = blockIdx.x * SROWS;
    for (int i = tid; i < SROWS; i += 512) sidx[i] = idx[nb0 + i];
    hist[tid] = 0;   // blockDim == KC == 512
    __syncthreads();
    for (int i = tid; i < SROWS; i += 512) atomicAdd(&hist[sidx[i] & (KC - 1)], 1);

    f32x4 acc[4][4];
#pragma unroll
    for (int a = 0; a < 4; ++a)
#pragma unroll
        for (int b = 0; b < 4; ++b) acc[a][b] = (f32x4){0.f, 0.f, 0.f, 0.f};

    for (int ch = 0; ch < SROWS / 64; ++ch) {
        __syncthreads();  // xpk reuse (and hist atomics done by first iter)
#pragma unroll
        for (int pp = 0; pp < 2; ++pp) {
            int flat = pp * 512 + tid;
            int r64 = flat >> 4, d4 = flat & 15;
            float4 v = ((const float4*)(x + (size_t)(nb0 + ch * 64 + r64) * D))[d4];
            float vals[4] = {v.x, v.y, v.z, v.w};
#pragma unroll
            for (int i = 0; i < 4; ++i) {
                unsigned short h = bf16_rne(vals[i]);
                int d = d4 * 4 + i;
                xpk[r64 * 64 + ((d + 2 * r64) & 63)] = (unsigned)h;
            }
        }
        __syncthreads();
#pragma unroll
        for (int s = 0; s < 2; ++s) {
            int iv[8];
#pragma unroll
            for (int j = 0; j < 8; ++j)
                iv[j] = sidx[ch * 64 + s * 32 + q * 8 + j];
            s8v af[4];
#pragma unroll
            for (int kt = 0; kt < 4; ++kt) {
                int tgt = w * 64 + kt * 16 + c16;
#pragma unroll
                for (int j = 0; j < 8; ++j)
                    af[kt][j] = (iv[j] == tgt) ? (short)0x3F80 : (short)0;
            }
#pragma unroll
            for (int dt = 0; dt < 4; ++dt) {
                s8v bh;
#pragma unroll
                for (int j = 0; j < 8; ++j) {
                    int n = s * 32 + q * 8 + j;
                    unsigned pv = xpk[n * 64 + ((dt * 16 + c16 + 2 * n) & 63)];
                    bh[j] = (short)(pv & 0xffff);
                }
#pragma unroll
                for (int kt = 0; kt < 4; ++kt) {
                    acc[kt][dt] = __builtin_amdgcn_mfma_f32_16x16x32_bf16(af[kt], bh, acc[kt][dt], 0, 0, 0);
                }
            }
        }
    }
    _Float16* gp = gpart + (size_t)blockIdx.x * (KC * D);
#pragma unroll
    for (int kt = 0; kt < 4; ++kt)
#pragma unroll
        for (int dt = 0; dt < 4; ++dt)
#pragma unroll
            for (int r = 0; r < 4; ++r) {
                int k = w * 64 + kt * 16 + q * 4 + r;
                gp[k * D + dt * 16 + c16] = (_Float16)acc[kt][dt][r];
            }
    __syncthreads();
    gcount[(size_t)blockIdx.x * KC + tid] = (float)hist[tid];
}

// ---- K3: one block per cluster: reduce gpart+gcount + EMA -> embedding_new --
// usage==0 clusters never appear in encoding_index -> flat[r] path is dead.
__global__ __launch_bounds__(256) void k_final(
    const _Float16* __restrict__ gpart, const float* __restrict__ gcount,
    const float* __restrict__ cnt_in, const float* __restrict__ sum_embed,
    float* __restrict__ embnew) {
    __shared__ float sp[4][64];
    __shared__ float cp[256];
    int k = blockIdx.x;               // 512 blocks = KC
    int tid = threadIdx.x;
    int d = tid & 63, g = tid >> 6;
    float s = 0.f;
    for (int c = g * 64; c < g * 64 + 64; ++c)
        s += (float)gpart[(size_t)c * (KC * D) + k * D + d];
    sp[g][d] = s;
    cp[tid] = gcount[(size_t)tid * KC + k];
    __syncthreads();
    if (g == 0) {
        float st = sp[0][d] + sp[1][d] + sp[2][d] + sp[3][d];
        float cv = cp[4 * d] + cp[4 * d + 1] + cp[4 * d + 2] + cp[4 * d + 3];
#pragma unroll
        for (int m = 1; m < 64; m <<= 1) cv += __shfl_xor(cv, m);
        float c0 = cnt_in[k];
        float cn = c0 + EMA_A * (cv - c0);
        float se0 = sum_embed[k * D + d];
        float se = se0 + EMA_A * (st - se0);
        embnew[k * D + d] = (cn >= 1.0f) ? (se / cn) : 0.0f;
    }
}

// ---- K4: gather out[n][:] = embnew[idx[n]][:] ----
// idx masked to [0,KC) so a poisoned idx can never read OOB (no-op when valid)
__global__ __launch_bounds__(256) void k_gather(const int* __restrict__ idx,
                                                const float* __restrict__ embnew,
                                                float* __restrict__ out, int N) {
    int g = blockIdx.x * 256 + threadIdx.x;
    int row = g >> 4, q = g & 15;
    if (row >= N) return;
    int k = idx[row] & (KC - 1);
    const float4* e4 = (const float4*)embnew;
    ((float4*)out)[(size_t)row * (D / 4) + q] = e4[k * (D / 4) + q];
}

extern "C" void kernel_launch(void* const* d_in, const int* in_sizes, int n_in,
                              void* d_out, int out_size, void* d_ws, size_t ws_size,
                              hipStream_t stream) {
    const float* x = (const float*)d_in[0];
    const float* emb = (const float*)d_in[1];
    const float* cnt = (const float*)d_in[2];
    const float* sum_embed = (const float*)d_in[3];
    float* out = (float*)d_out;
    int N = in_sizes[0] / D;  // 262144

    char* w = (char*)d_ws;
    size_t off = 0;
    int* idx = (int*)(w + off);        off += (size_t)N * 4;                 // 1 MB
    int* wlist = (int*)(w + off);      off += (size_t)N * 4;                 // 1 MB
    int* wcount = (int*)(w + off);     off += 16;
    float* he = (float*)(w + off);     off += (size_t)KC * 4;                // 2 KB
    short* gB = (short*)(w + off);     off += (size_t)8 * 8192 * 2;          // 128 KB
    float* embnew = (float*)(w + off); off += (size_t)KC * D * 4;            // 128 KB
    float* gcount = (float*)(w + off); off += (size_t)NCHUNK * KC * 4;       // 512 KB
    _Float16* gpart = (_Float16*)(w + off);
    off += (size_t)NCHUNK * KC * D * 2;                                      // 16 MB
    // total ~19.7 MB

    k_prep<<<(KC + 255) / 256, 256, 0, stream>>>(emb, he, gB, wcount);
    k_assign<<<N / 256, 512, 0, stream>>>(x, gB, he, idx, wlist, wcount);
    k_recheck<<<512, 256, 0, stream>>>(x, emb, he, wlist, wcount, idx, N);
    k_segsum<<<NCHUNK, 512, 0, stream>>>(x, idx, gpart, gcount);
    k_final<<<KC, 256, 0, stream>>>(gpart, gcount, cnt, sum_embed, embnew);
    k_gather<<<((size_t)N * (D / 4)) / 256, 256, 0, stream>>>(idx, embnew, out, N);
}

// Round 17
// 259.364 us; speedup vs baseline: 1.1402x; 1.0617x over previous
//
#include <hip/hip_runtime.h>

#define D 64
#define KC 512
#define EMA_A 0.01f
#define SROWS 1024     // rows per segsum block
#define NCHUNK 256     // N / SROWS (gpart + gcount partials)
#define BAND 0.0078125f // recheck band; 3-term split err ~7e-4 -> 5.6x margin
                        // (was 0.0156/22x; halves worklist -> k_recheck ~-50%)

typedef float f32x4 __attribute__((ext_vector_type(4)));
typedef float v4f __attribute__((ext_vector_type(4)));
typedef short s8v __attribute__((ext_vector_type(8)));   // 8 bf16 as shorts
typedef short s4v __attribute__((ext_vector_type(4)));

__device__ inline unsigned short bf16_rne(float f) {
    unsigned u = __float_as_uint(f);
    return (unsigned short)((u + 0x7fffu + ((u >> 16) & 1u)) >> 16);
}
__device__ inline float bf16_f(unsigned short h) {
    return __uint_as_float(((unsigned)h) << 16);
}
__device__ inline float med3f(float a, float b, float c) {
#if __has_builtin(__builtin_amdgcn_fmed3f)
    return __builtin_amdgcn_fmed3f(a, b, c);
#else
    return fmaxf(fminf(a, fmaxf(b, c)), fminf(b, c));
#endif
}

// ---- K0: he[k] = 0.5*||emb_k||^2 ; pre-SWIZZLED bf16 hi/lo B images
//          (XOR swizzle: B consumed via ds_read_b128) ; zero worklist ----
__global__ __launch_bounds__(256) void k_prep(const float* __restrict__ emb,
                                              float* __restrict__ he,
                                              short* __restrict__ gB,
                                              int* __restrict__ wcount) {
    if (blockIdx.x == 0 && threadIdx.x == 0) wcount[0] = 0;
    int k = blockIdx.x * 256 + threadIdx.x;
    if (k >= KC) return;
    int c8 = k >> 6, c = k & 63;
    short* dst = gB + (size_t)c8 * 8192;
    float s = 0.f;
#pragma unroll
    for (int kq = 0; kq < 16; ++kq) {
        float4 v = ((const float4*)(emb + (size_t)k * D))[kq];
        s = fmaf(v.x, v.x, s); s = fmaf(v.y, v.y, s);
        s = fmaf(v.z, v.z, s); s = fmaf(v.w, v.w, s);
        unsigned short h0 = bf16_rne(v.x), h1 = bf16_rne(v.y);
        unsigned short h2 = bf16_rne(v.z), h3 = bf16_rne(v.w);
        s4v hv = {(short)h0, (short)h1, (short)h2, (short)h3};
        s4v lv = {(short)bf16_rne(v.x - bf16_f(h0)),
                  (short)bf16_rne(v.y - bf16_f(h1)),
                  (short)bf16_rne(v.z - bf16_f(h2)),
                  (short)bf16_rne(v.w - bf16_f(h3))};
        int si = c * 64 + (((kq >> 1) ^ (c & 7)) * 8) + (kq & 1) * 4;
        *(s4v*)(&dst[si]) = hv;
        *(s4v*)(&dst[4096 + si]) = lv;
    }
    he[k] = 0.5f * s;
}

// ---- K1: MFMA 3-term split-bf16 argmin — whole-B-in-LDS, zero-barrier loop.
// = r14/r16 champion (83us, 88 VGPR, no spill). Occupancy arc closed:
// every pinned-bound / half-LDS variant (r10-r15) spilled or got phantom
// occupancy. 128KiB whole-B + plain bounds lets the allocator pick 88 regs.
// he-fold + max-form med3 tracking (validated r10-r16).
__global__ __launch_bounds__(512) void k_assign(
    const float* __restrict__ x, const short* __restrict__ gB,
    const float* __restrict__ he, int* __restrict__ idx,
    int* __restrict__ wlist, int* __restrict__ wcount) {
    __shared__ __align__(16) short LB[65536];  // 128 KiB exactly
    int tid = threadIdx.x;
    int lane = tid & 63, w = tid >> 6, q = lane >> 4, c16 = lane & 15;
    size_t R0 = (size_t)blockIdx.x * 256;   // 256 rows per block

    // stage full pre-swizzled B image: 8192 int4 over 512 threads
    {
        const int4* gsrc = (const int4*)gB;
        int4* ldst = (int4*)LB;
#pragma unroll
        for (int p = 0; p < 16; ++p) ldst[p * 512 + tid] = gsrc[p * 512 + tid];
    }

    // A fragments for 2 M-tiles: lane (c16,q) of wave w owns rows
    // w*32 + mt*16 + c16, k-group g = ks*4+q. Convert to bf16 hi/lo.
    s8v ah[2][2], al[2][2];
#pragma unroll
    for (int mt = 0; mt < 2; ++mt) {
        const float* xr = x + (R0 + (size_t)(w * 32 + mt * 16 + c16)) * D;
#pragma unroll
        for (int ks = 0; ks < 2; ++ks) {
            int g = ks * 4 + q;
            f32x4 v0 = *(const f32x4*)(xr + g * 8);
            f32x4 v1 = *(const f32x4*)(xr + g * 8 + 4);
#pragma unroll
            for (int j = 0; j < 4; ++j) {
                unsigned short h0 = bf16_rne(v0[j]);
                ah[mt][ks][j] = (short)h0;
                al[mt][ks][j] = (short)bf16_rne(v0[j] - bf16_f(h0));
                unsigned short h1 = bf16_rne(v1[j]);
                ah[mt][ks][4 + j] = (short)h1;
                al[mt][ks][4 + j] = (short)bf16_rne(v1[j] - bf16_f(h1));
            }
        }
    }
    __syncthreads();   // B image staged (the only barrier before epilogue)

    // max-form tracking: s = dot - he = -d; argmin d == argmax s
    float m1[2][4], m2[2][4]; int i1[2][4];
#pragma unroll
    for (int mt = 0; mt < 2; ++mt)
#pragma unroll
        for (int e = 0; e < 4; ++e) {
            m1[mt][e] = -3.4e38f; m2[mt][e] = -3.4e38f; i1[mt][e] = 0;
        }

#pragma unroll
    for (int c8 = 0; c8 < 8; ++c8) {
        const short* B = LB + c8 * 8192;
#pragma unroll
        for (int ct = 0; ct < 4; ++ct) {
            int c = ct * 16 + c16;
            s8v bh[2], bl[2];
#pragma unroll
            for (int ks = 0; ks < 2; ++ks) {
                int kb = (ks * 4 + q) ^ (c & 7);
                bh[ks] = *(const s8v*)(&B[c * 64 + kb * 8]);
                bl[ks] = *(const s8v*)(&B[4096 + c * 64 + kb * 8]);
            }
            int cbase = c8 * 64 + ct * 16;
            float hn = -he[cbase + c16];
            int ci = cbase + c16;
#pragma unroll
            for (int mt = 0; mt < 2; ++mt) {
                f32x4 a0 = {hn, hn, hn, hn};   // C-init = -he
                f32x4 a1 = {0.f, 0.f, 0.f, 0.f};
                a0 = __builtin_amdgcn_mfma_f32_16x16x32_bf16(ah[mt][0], bh[0], a0, 0, 0, 0);
                a0 = __builtin_amdgcn_mfma_f32_16x16x32_bf16(ah[mt][1], bh[1], a0, 0, 0, 0);
                a0 = __builtin_amdgcn_mfma_f32_16x16x32_bf16(ah[mt][0], bl[0], a0, 0, 0, 0);
                a0 = __builtin_amdgcn_mfma_f32_16x16x32_bf16(ah[mt][1], bl[1], a0, 0, 0, 0);
                a1 = __builtin_amdgcn_mfma_f32_16x16x32_bf16(al[mt][0], bh[0], a1, 0, 0, 0);
                a1 = __builtin_amdgcn_mfma_f32_16x16x32_bf16(al[mt][1], bh[1], a1, 0, 0, 0);
#pragma unroll
                for (int r = 0; r < 4; ++r) {
                    float s = a0[r] + a1[r];
                    m2[mt][r] = med3f(s, m2[mt][r], m1[mt][r]);  // 2nd-max
                    bool gt = s > m1[mt][r];            // strict: first-max
                    i1[mt][r] = gt ? ci : i1[mt][r];
                    m1[mt][r] = fmaxf(m1[mt][r], s);
                }
            }
        }
    }
    // reduce (m1,i1,m2) across the 16 lanes of each quad group (max-form)
#pragma unroll
    for (int m = 1; m < 16; m <<= 1) {
#pragma unroll
        for (int mt = 0; mt < 2; ++mt)
#pragma unroll
            for (int e = 0; e < 4; ++e) {
                float om1 = __shfl_xor(m1[mt][e], m);
                float om2 = __shfl_xor(m2[mt][e], m);
                int oi = __shfl_xor(i1[mt][e], m);
                float nm2 = fmaxf(fmaxf(m2[mt][e], om2), fminf(m1[mt][e], om1));
                bool take = (om1 > m1[mt][e]) || (om1 == m1[mt][e] && oi < i1[mt][e]);
                i1[mt][e] = take ? oi : i1[mt][e];
                m1[mt][e] = fmaxf(m1[mt][e], om1);
                m2[mt][e] = nm2;
            }
    }
    // ---- epilogue: worklist aliases into LB (B image is dead now) ----
    __syncthreads();                    // all waves done reading LB
    int* wl = (int*)LB;                 // wl[0]=cnt, wl[1]=base, wl[2..]=rows
    if (tid == 0) wl[0] = 0;
    __syncthreads();
    if (c16 == 0) {
#pragma unroll
        for (int mt = 0; mt < 2; ++mt)
#pragma unroll
            for (int e = 0; e < 4; ++e) {
                int row = (int)R0 + w * 32 + mt * 16 + q * 4 + e;
                idx[row] = i1[mt][e];
                if (m1[mt][e] - m2[mt][e] < BAND) {   // margin band (max-form)
                    int p = atomicAdd(&wl[0], 1);     // LDS atomic; max 256
                    wl[2 + p] = row;
                }
            }
    }
    __syncthreads();
    if (tid == 0 && wl[0] > 0) wl[1] = atomicAdd(wcount, wl[0]);
    __syncthreads();
    int wcnt = wl[0];
    for (int i = tid; i < wcnt; i += 512) wlist[wl[1] + i] = wl[2 + i];
}

// ---- K1b: exact fp32 rescan, one WAVE per worklist row ----
// hardened: clamp cnt and row so poisoned workspace can never go OOB
__global__ __launch_bounds__(256) void k_recheck(
    const float* __restrict__ x, const float* __restrict__ emb,
    const float* __restrict__ he, const int* __restrict__ wlist,
    const int* __restrict__ wcount, int* __restrict__ idx, int nrows) {
    int lane = threadIdx.x & 63;
    int wave = (blockIdx.x * 256 + threadIdx.x) >> 6;
    int nwaves = (gridDim.x * 256) >> 6;
    int cnt = wcount[0];
    if (cnt < 0) cnt = 0;
    if (cnt > nrows) cnt = nrows;
    for (int i = wave; i < cnt; i += nwaves) {
        int row = wlist[i];
        if ((unsigned)row >= (unsigned)nrows) continue;  // defensive
        const v4f* xr = (const v4f*)(x + (size_t)row * D);
        v4f X[16];
#pragma unroll
        for (int t = 0; t < 16; ++t) X[t] = xr[t];
        float bd = 3.4e38f; int bi = 0x7fffffff;
#pragma unroll
        for (int j = 0; j < 8; ++j) {
            int c = j * 64 + lane;
            const v4f* er = (const v4f*)(emb + (size_t)c * D);
            v4f s = X[0] * er[0];
#pragma unroll
            for (int t = 1; t < 16; ++t) s += X[t] * er[t];
            float dot = (s.x + s.y) + (s.z + s.w);
            float d = he[c] - dot;
            if (d < bd) { bd = d; bi = c; }
        }
#pragma unroll
        for (int m = 1; m < 64; m <<= 1) {
            float od = __shfl_xor(bd, m);
            int oi = __shfl_xor(bi, m);
            if (od < bd || (od == bd && oi < bi)) { bd = od; bi = oi; }
        }
        if (lane == 0) idx[row] = bi;
    }
}

// ---- K2: MFMA one-hot segment sums + FUSED count histogram ----
// HI-ONLY bf16 x image (validated r16: absmax unchanged at 0.0078).
// gpart partials stored as fp16 (validated r1+).
__global__ __launch_bounds__(512, 1) void k_segsum(
    const float* __restrict__ x, const int* __restrict__ idx,
    _Float16* __restrict__ gpart, float* __restrict__ gcount) {
    __shared__ int sidx[SROWS];          // 4 KB
    __shared__ unsigned xpk[64 * 64];    // 16 KB (hi in low 16 bits)
    __shared__ int hist[KC];             // 2 KB
    int tid = threadIdx.x;
    int lane = tid & 63, w = tid >> 6, q = lane >> 4, c16 = lane & 15;
    int nb0 = blockIdx.x * SROWS;
    for (int i = tid; i < SROWS; i += 512) sidx[i] = idx[nb0 + i];
    hist[tid] = 0;   // blockDim == KC == 512
    __syncthreads();
    for (int i = tid; i < SROWS; i += 512) atomicAdd(&hist[sidx[i] & (KC - 1)], 1);

    f32x4 acc[4][4];
#pragma unroll
    for (int a = 0; a < 4; ++a)
#pragma unroll
        for (int b = 0; b < 4; ++b) acc[a][b] = (f32x4){0.f, 0.f, 0.f, 0.f};

    for (int ch = 0; ch < SROWS / 64; ++ch) {
        __syncthreads();  // xpk reuse (and hist atomics done by first iter)
#pragma unroll
        for (int pp = 0; pp < 2; ++pp) {
            int flat = pp * 512 + tid;
            int r64 = flat >> 4, d4 = flat & 15;
            float4 v = ((const float4*)(x + (size_t)(nb0 + ch * 64 + r64) * D))[d4];
            float vals[4] = {v.x, v.y, v.z, v.w};
#pragma unroll
            for (int i = 0; i < 4; ++i) {
                unsigned short h = bf16_rne(vals[i]);
                int d = d4 * 4 + i;
                xpk[r64 * 64 + ((d + 2 * r64) & 63)] = (unsigned)h;
            }
        }
        __syncthreads();
#pragma unroll
        for (int s = 0; s < 2; ++s) {
            int iv[8];
#pragma unroll
            for (int j = 0; j < 8; ++j)
                iv[j] = sidx[ch * 64 + s * 32 + q * 8 + j];
            s8v af[4];
#pragma unroll
            for (int kt = 0; kt < 4; ++kt) {
                int tgt = w * 64 + kt * 16 + c16;
#pragma unroll
                for (int j = 0; j < 8; ++j)
                    af[kt][j] = (iv[j] == tgt) ? (short)0x3F80 : (short)0;
            }
#pragma unroll
            for (int dt = 0; dt < 4; ++dt) {
                s8v bh;
#pragma unroll
                for (int j = 0; j < 8; ++j) {
                    int n = s * 32 + q * 8 + j;
                    unsigned pv = xpk[n * 64 + ((dt * 16 + c16 + 2 * n) & 63)];
                    bh[j] = (short)(pv & 0xffff);
                }
#pragma unroll
                for (int kt = 0; kt < 4; ++kt) {
                    acc[kt][dt] = __builtin_amdgcn_mfma_f32_16x16x32_bf16(af[kt], bh, acc[kt][dt], 0, 0, 0);
                }
            }
        }
    }
    _Float16* gp = gpart + (size_t)blockIdx.x * (KC * D);
#pragma unroll
    for (int kt = 0; kt < 4; ++kt)
#pragma unroll
        for (int dt = 0; dt < 4; ++dt)
#pragma unroll
            for (int r = 0; r < 4; ++r) {
                int k = w * 64 + kt * 16 + q * 4 + r;
                gp[k * D + dt * 16 + c16] = (_Float16)acc[kt][dt][r];
            }
    __syncthreads();
    gcount[(size_t)blockIdx.x * KC + tid] = (float)hist[tid];
}

// ---- K3: one block per cluster: reduce gpart+gcount + EMA -> embedding_new --
// usage==0 clusters never appear in encoding_index -> flat[r] path is dead.
__global__ __launch_bounds__(256) void k_final(
    const _Float16* __restrict__ gpart, const float* __restrict__ gcount,
    const float* __restrict__ cnt_in, const float* __restrict__ sum_embed,
    float* __restrict__ embnew) {
    __shared__ float sp[4][64];
    __shared__ float cp[256];
    int k = blockIdx.x;               // 512 blocks = KC
    int tid = threadIdx.x;
    int d = tid & 63, g = tid >> 6;
    float s = 0.f;
    for (int c = g * 64; c < g * 64 + 64; ++c)
        s += (float)gpart[(size_t)c * (KC * D) + k * D + d];
    sp[g][d] = s;
    cp[tid] = gcount[(size_t)tid * KC + k];
    __syncthreads();
    if (g == 0) {
        float st = sp[0][d] + sp[1][d] + sp[2][d] + sp[3][d];
        float cv = cp[4 * d] + cp[4 * d + 1] + cp[4 * d + 2] + cp[4 * d + 3];
#pragma unroll
        for (int m = 1; m < 64; m <<= 1) cv += __shfl_xor(cv, m);
        float c0 = cnt_in[k];
        float cn = c0 + EMA_A * (cv - c0);
        float se0 = sum_embed[k * D + d];
        float se = se0 + EMA_A * (st - se0);
        embnew[k * D + d] = (cn >= 1.0f) ? (se / cn) : 0.0f;
    }
}

// ---- K4: gather out[n][:] = embnew[idx[n]][:] ----
// idx masked to [0,KC) so a poisoned idx can never read OOB (no-op when valid)
__global__ __launch_bounds__(256) void k_gather(const int* __restrict__ idx,
                                                const float* __restrict__ embnew,
                                                float* __restrict__ out, int N) {
    int g = blockIdx.x * 256 + threadIdx.x;
    int row = g >> 4, q = g & 15;
    if (row >= N) return;
    int k = idx[row] & (KC - 1);
    const float4* e4 = (const float4*)embnew;
    ((float4*)out)[(size_t)row * (D / 4) + q] = e4[k * (D / 4) + q];
}

extern "C" void kernel_launch(void* const* d_in, const int* in_sizes, int n_in,
                              void* d_out, int out_size, void* d_ws, size_t ws_size,
                              hipStream_t stream) {
    const float* x = (const float*)d_in[0];
    const float* emb = (const float*)d_in[1];
    const float* cnt = (const float*)d_in[2];
    const float* sum_embed = (const float*)d_in[3];
    float* out = (float*)d_out;
    int N = in_sizes[0] / D;  // 262144

    char* w = (char*)d_ws;
    size_t off = 0;
    int* idx = (int*)(w + off);        off += (size_t)N * 4;                 // 1 MB
    int* wlist = (int*)(w + off);      off += (size_t)N * 4;                 // 1 MB
    int* wcount = (int*)(w + off);     off += 16;
    float* he = (float*)(w + off);     off += (size_t)KC * 4;                // 2 KB
    short* gB = (short*)(w + off);     off += (size_t)8 * 8192 * 2;          // 128 KB
    float* embnew = (float*)(w + off); off += (size_t)KC * D * 4;            // 128 KB
    float* gcount = (float*)(w + off); off += (size_t)NCHUNK * KC * 4;       // 512 KB
    _Float16* gpart = (_Float16*)(w + off);
    off += (size_t)NCHUNK * KC * D * 2;                                      // 16 MB
    // total ~19.7 MB

    k_prep<<<(KC + 255) / 256, 256, 0, stream>>>(emb, he, gB, wcount);
    k_assign<<<N / 256, 512, 0, stream>>>(x, gB, he, idx, wlist, wcount);
    k_recheck<<<512, 256, 0, stream>>>(x, emb, he, wlist, wcount, idx, N);
    k_segsum<<<NCHUNK, 512, 0, stream>>>(x, idx, gpart, gcount);
    k_final<<<KC, 256, 0, stream>>>(gpart, gcount, cnt, sum_embed, embnew);
    k_gather<<<((size_t)N * (D / 4)) / 256, 256, 0, stream>>>(idx, embnew, out, N);
}